// Round 1
// baseline (479.309 us; speedup 1.0000x reference)
//
#include <hip/hip_runtime.h>
#include <math.h>

typedef short short8 __attribute__((ext_vector_type(8)));
typedef float floatx4 __attribute__((ext_vector_type(4)));

#define TEMP_INV 5.0f
#define W_UNSUP 0.2f
#define NB_BCE 256
#define NSPLIT 4

static __device__ __forceinline__ unsigned short f2bf(float f) {
  unsigned int u = __float_as_uint(f);
  u += 0x7FFFu + ((u >> 16) & 1u);
  return (unsigned short)(u >> 16);
}

__device__ __forceinline__ float block_sum256(float v) {
  __shared__ float sh[4];
  for (int m = 1; m <= 32; m <<= 1) v += __shfl_xor(v, m);
  __syncthreads();
  if ((threadIdx.x & 63) == 0) sh[threadIdx.x >> 6] = v;
  __syncthreads();
  return sh[0] + sh[1] + sh[2] + sh[3];
}

// Detect train_mask storage: 0 = int32 {0,1}, 1 = float32 {0,1.0f}, 2 = raw bytes
__global__ void detect_kernel(const unsigned int* __restrict__ w, int nw, int* __restrict__ flag) {
  __shared__ int s_int, s_flt;
  if (threadIdx.x == 0) { s_int = 1; s_flt = 1; }
  __syncthreads();
  for (int i = threadIdx.x; i < nw; i += blockDim.x) {
    unsigned int x = w[i];
    if (x != 0u && x != 1u) s_int = 0;
    if (x != 0u && x != 0x3F800000u) s_flt = 0;
  }
  __syncthreads();
  if (threadIdx.x == 0) *flag = s_int ? 0 : (s_flt ? 1 : 2);
}

__global__ __launch_bounds__(256) void bce_kernel(
    const float* __restrict__ fused, const float* __restrict__ viewl,
    const float* __restrict__ labels, const void* __restrict__ maskp,
    const int* __restrict__ flagp, float* __restrict__ partials, int N, int V) {
  const int flag = *flagp;
  float cnt = 0.f, sm = 0.f;
  float sv[8];
  for (int v = 0; v < 8; v++) sv[v] = 0.f;
  const int Vc = V > 8 ? 8 : V;
  for (int i = blockIdx.x * blockDim.x + threadIdx.x; i < N; i += gridDim.x * blockDim.x) {
    bool m;
    if (flag == 0)      m = ((const int*)maskp)[i] != 0;
    else if (flag == 1) m = ((const float*)maskp)[i] != 0.0f;
    else                m = ((const unsigned char*)maskp)[i] != 0;
    if (!m) continue;
    float y = labels[i];
    cnt += 1.0f;
    float x = fused[i];
    sm += fmaxf(x, 0.f) - x * y + log1pf(__expf(-fabsf(x)));
    for (int v = 0; v < Vc; v++) {
      float xv = viewl[(size_t)v * N + i];
      sv[v] += fmaxf(xv, 0.f) - xv * y + log1pf(__expf(-fabsf(xv)));
    }
  }
  float tot = block_sum256(cnt);
  if (threadIdx.x == 0) partials[blockIdx.x * 16 + 0] = tot;
  tot = block_sum256(sm);
  if (threadIdx.x == 0) partials[blockIdx.x * 16 + 1] = tot;
  for (int v = 0; v < Vc; v++) {
    tot = block_sum256(sv[v]);
    if (threadIdx.x == 0) partials[blockIdx.x * 16 + 2 + v] = tot;
  }
}

// Gather rows into bf16 matrices; compute per-row diag (||z||^2/temp), normalize for unsup.
__global__ __launch_bounds__(256) void gather_kernel(
    const float* __restrict__ proj, const int* __restrict__ pos_idx,
    const int* __restrict__ neg_idx, const int* __restrict__ unl_idx,
    unsigned short* __restrict__ zsup, unsigned short* __restrict__ zuns,
    float* __restrict__ dsup, float* __restrict__ duns,
    int N, int D, int V, int P, int Msup, int Muns) {
  const int prob = blockIdx.y;
  const int r = blockIdx.x;
  const int M = prob ? Muns : Msup;
  if (r >= M) return;
  const int l = r / V, v = r - l * V;
  const int idx = prob ? unl_idx[l] : (l < P ? pos_idx[l] : neg_idx[l - P]);
  const float* src = proj + ((size_t)v * N + (size_t)idx) * D;
  const int t = threadIdx.x;
  float s = 0.f;
  for (int d = t; d < D; d += blockDim.x) { float x = src[d]; s += x * x; }
  for (int m = 1; m <= 32; m <<= 1) s += __shfl_xor(s, m);
  __shared__ float sh[4];
  if ((t & 63) == 0) sh[t >> 6] = s;
  __syncthreads();
  const float n2 = sh[0] + sh[1] + sh[2] + sh[3];
  if (prob == 0) {
    for (int d = t; d < D; d += blockDim.x) zsup[(size_t)r * D + d] = f2bf(src[d]);
    if (t == 0) dsup[r] = n2 * TEMP_INV;
  } else {
    const float sc = 1.0f / (sqrtf(n2) + 1e-8f);
    for (int d = t; d < D; d += blockDim.x) zuns[(size_t)r * D + d] = f2bf(src[d] * sc);
    if (t == 0) duns[r] = n2 * sc * sc * TEMP_INV;
  }
}

// Big kernel: sim = Z Z^T / temp via bf16 MFMA; per-row accumulate
//   E = sum_j exp(sim - 5)   (incl. diagonal, subtracted in finalize)
//   B = sum_{j in [bs,be)} sim  (contiguous positive block, incl. diagonal)
// Grid: (NSPLIT col-splits, M/64 row strips, 2 problems). 256 thr = 4 waves, 16 rows/wave.
__global__ __launch_bounds__(256) void sim_kernel(
    const unsigned short* __restrict__ zsup, const unsigned short* __restrict__ zuns,
    float* __restrict__ Esup, float* __restrict__ Bsup,
    float* __restrict__ Euns, float* __restrict__ Buns,
    int Msup, int Muns, int PV, int V) {
  const int prob = blockIdx.z;
  const unsigned short* __restrict__ z = prob ? zuns : zsup;
  float* __restrict__ Ep = prob ? Euns : Esup;
  float* __restrict__ Bp = prob ? Buns : Bsup;
  const int M = prob ? Muns : Msup;

  const int tid = threadIdx.x;
  const int lane = tid & 63;
  const int wave = tid >> 6;
  const int q = lane >> 4;
  const int n16 = lane & 15;

  const int rowBase = blockIdx.y * 64 + wave * 16;

  // A fragments: 16 rows x K=256 resident in registers.
  // Layout per guide: A[m = lane&15][k = q*8 + j], j=0..7, k-step 32 per mfma.
  int arow = rowBase + n16; if (arow >= M) arow = M - 1;
  short8 afrag[8];
  {
    const unsigned short* zr = z + (size_t)arow * 256 + q * 8;
#pragma unroll
    for (int ks = 0; ks < 8; ks++) afrag[ks] = *(const short8*)(zr + ks * 32);
  }

  int bs[4], be[4];
#pragma unroll
  for (int r = 0; r < 4; r++) {
    int row = rowBase + q * 4 + r;
    if (row >= M) row = M - 1;
    if (prob == 0) { bs[r] = (row < PV) ? 0 : PV; be[r] = (row < PV) ? PV : M; }
    else           { int b0 = (row / V) * V; bs[r] = b0; be[r] = b0 + V; }
  }

  float Eacc[4] = {0.f, 0.f, 0.f, 0.f};
  float Bacc[4] = {0.f, 0.f, 0.f, 0.f};

  // 64 col rows x 256 k, +8 bf16 pad per row -> ds_read_b128 is 2-way (free) conflict
  __shared__ __align__(16) unsigned short lds[64 * 264];

  int cps = ((M + NSPLIT * 64 - 1) / (NSPLIT * 64)) * 64;  // cols per split, x64
  int colStart = blockIdx.x * cps;
  int colEnd = colStart + cps; if (colEnd > M) colEnd = M;

  for (int c0 = colStart; c0 < colEnd; c0 += 64) {
    __syncthreads();
#pragma unroll
    for (int cc = 0; cc < 8; cc++) {
      int chunk = cc * 256 + tid;        // 2048 chunks of 16B
      int rrow = chunk >> 5;
      int off = (chunk & 31) * 8;
      int gcol = c0 + rrow;
      short8 vv = {0, 0, 0, 0, 0, 0, 0, 0};
      if (gcol < M) vv = *(const short8*)(z + (size_t)gcol * 256 + off);
      *(short8*)(&lds[rrow * 264 + off]) = vv;
    }
    __syncthreads();

#pragma unroll
    for (int cb = 0; cb < 4; cb++) {
      floatx4 acc = {0.f, 0.f, 0.f, 0.f};
      const unsigned short* bp = &lds[(cb * 16 + n16) * 264 + q * 8];
#pragma unroll
      for (int ks = 0; ks < 8; ks++) {
        short8 bfrag = *(const short8*)(bp + ks * 32);
        acc = __builtin_amdgcn_mfma_f32_16x16x32_bf16(afrag[ks], bfrag, acc, 0, 0, 0);
      }
      int j = c0 + cb * 16 + n16;
      if (j < M) {
#pragma unroll
        for (int r = 0; r < 4; r++) {
          float t = acc[r] * TEMP_INV;
          Eacc[r] += __expf(t - 5.0f);
          Bacc[r] += (j >= bs[r] && j < be[r]) ? t : 0.0f;
        }
      }
    }
  }

  // reduce across the 16 lanes sharing (wave, q); C-row = rowBase + q*4 + r
#pragma unroll
  for (int r = 0; r < 4; r++) {
    float e = Eacc[r], b = Bacc[r];
    for (int m = 1; m <= 8; m <<= 1) { e += __shfl_xor(e, m); b += __shfl_xor(b, m); }
    int row = rowBase + q * 4 + r;
    if (n16 == 0 && row < M) {
      Ep[(size_t)blockIdx.x * M + row] = e;
      Bp[(size_t)blockIdx.x * M + row] = b;
    }
  }
}

__global__ __launch_bounds__(256) void finalize_kernel(
    const float* __restrict__ partials,
    const float* __restrict__ Esup, const float* __restrict__ Bsup, const float* __restrict__ dsup,
    const float* __restrict__ Euns, const float* __restrict__ Buns, const float* __restrict__ duns,
    int Msup, int Muns, int PV, int P, int NEG, int V, float* __restrict__ out) {
  const int t = threadIdx.x;
  float cnt = 0.f, sm = 0.f, sv[8];
  for (int v = 0; v < 8; v++) sv[v] = 0.f;
  const int Vc = V > 8 ? 8 : V;
  for (int b = t; b < NB_BCE; b += 256) {
    cnt += partials[b * 16 + 0];
    sm  += partials[b * 16 + 1];
    for (int v = 0; v < Vc; v++) sv[v] += partials[b * 16 + 2 + v];
  }
  cnt = block_sum256(cnt);
  sm = block_sum256(sm);
  float svt = 0.f;
  for (int v = 0; v < Vc; v++) svt += block_sum256(sv[v]);
  const float denomC = fmaxf(cnt, 1.0f);
  const float main_loss = sm / denomC;
  const float view_loss = (svt / denomC) / (float)V;

  // sup: per-anchor = log(E - exp(d-5)) + 5 - (B - d)/pos_count
  float ssup = 0.f;
  for (int row = t; row < Msup; row += 256) {
    float E = 0.f, B = 0.f;
    for (int s = 0; s < NSPLIT; s++) {
      E += Esup[(size_t)s * Msup + row];
      B += Bsup[(size_t)s * Msup + row];
    }
    float d = dsup[row];
    float dn = E - __expf(d - 5.0f);
    float cl = (row < PV) ? (float)P : (float)NEG;
    float pc = (float)(V - 1) + (cl - 1.0f) * (float)V;
    ssup += logf(dn) + 5.0f - (B - d) / pc;
  }
  ssup = block_sum256(ssup);
  const float sup_loss = ssup / (float)Msup;

  // unsup: per-anchor = log(E - exp(d-5)) + 5 - (B - d)/(V-1)
  float suns = 0.f;
  for (int row = t; row < Muns; row += 256) {
    float E = 0.f, B = 0.f;
    for (int s = 0; s < NSPLIT; s++) {
      E += Euns[(size_t)s * Muns + row];
      B += Buns[(size_t)s * Muns + row];
    }
    float d = duns[row];
    float dn = E - __expf(d - 5.0f);
    suns += logf(dn) + 5.0f - (B - d) / (float)(V - 1);
  }
  suns = block_sum256(suns);
  const float unsup_loss = suns / (float)Muns;

  if (t == 0) {
    float total = main_loss + view_loss + sup_loss + W_UNSUP * unsup_loss;
    out[0] = total;
    out[1] = main_loss;
    out[2] = view_loss;
    out[3] = sup_loss;
    out[4] = unsup_loss;
  }
}

extern "C" void kernel_launch(void* const* d_in, const int* in_sizes, int n_in,
                              void* d_out, int out_size, void* d_ws, size_t ws_size,
                              hipStream_t stream) {
  const float* fused  = (const float*)d_in[0];
  const float* viewl  = (const float*)d_in[1];
  const float* proj   = (const float*)d_in[2];
  const float* labels = (const float*)d_in[3];
  const void*  maskp  = d_in[4];
  const int* pos_idx  = (const int*)d_in[5];
  const int* neg_idx  = (const int*)d_in[6];
  const int* unl_idx  = (const int*)d_in[7];

  const int N = in_sizes[0];
  const int V = in_sizes[1] / N;
  const int D = in_sizes[2] / in_sizes[1];   // = 256
  const int P = in_sizes[5];
  const int NEG = in_sizes[6];
  const int U = in_sizes[7];
  const int L = P + NEG;
  const int Msup = L * V;
  const int Muns = U * V;
  const int PV = P * V;

  char* ws = (char*)d_ws;
  size_t off = 0;
  auto alloc = [&](size_t bytes) { size_t o = off; off += (bytes + 255) & ~(size_t)255; return o; };
  const size_t o_flag = alloc(4);
  const size_t o_part = alloc((size_t)NB_BCE * 16 * 4);
  const size_t o_zsup = alloc((size_t)Msup * D * 2);
  const size_t o_zuns = alloc((size_t)Muns * D * 2);
  const size_t o_dsup = alloc((size_t)Msup * 4);
  const size_t o_duns = alloc((size_t)Muns * 4);
  const size_t o_Esup = alloc((size_t)NSPLIT * Msup * 4);
  const size_t o_Bsup = alloc((size_t)NSPLIT * Msup * 4);
  const size_t o_Euns = alloc((size_t)NSPLIT * Muns * 4);
  const size_t o_Buns = alloc((size_t)NSPLIT * Muns * 4);

  int* flag = (int*)(ws + o_flag);
  float* partials = (float*)(ws + o_part);
  unsigned short* zsup = (unsigned short*)(ws + o_zsup);
  unsigned short* zuns = (unsigned short*)(ws + o_zuns);
  float* dsup = (float*)(ws + o_dsup);
  float* duns = (float*)(ws + o_duns);
  float* Esup = (float*)(ws + o_Esup);
  float* Bsup = (float*)(ws + o_Bsup);
  float* Euns = (float*)(ws + o_Euns);
  float* Buns = (float*)(ws + o_Buns);

  int nw = N / 4 < 256 ? N / 4 : 256;
  detect_kernel<<<1, 256, 0, stream>>>((const unsigned int*)maskp, nw, flag);
  bce_kernel<<<NB_BCE, 256, 0, stream>>>(fused, viewl, labels, maskp, flag, partials, N, V);

  const int Mmax = Msup > Muns ? Msup : Muns;
  dim3 ggrid(Mmax, 2);
  gather_kernel<<<ggrid, 256, 0, stream>>>(proj, pos_idx, neg_idx, unl_idx,
                                           zsup, zuns, dsup, duns, N, D, V, P, Msup, Muns);

  dim3 sgrid(NSPLIT, (Mmax + 63) / 64, 2);
  sim_kernel<<<sgrid, 256, 0, stream>>>(zsup, zuns, Esup, Bsup, Euns, Buns, Msup, Muns, PV, V);

  finalize_kernel<<<1, 256, 0, stream>>>(partials, Esup, Bsup, dsup, Euns, Buns, duns,
                                         Msup, Muns, PV, P, NEG, V, (float*)d_out);
}